// Round 1
// baseline (984.799 us; speedup 1.0000x reference)
//
#include <hip/hip_runtime.h>
#include <cstdint>
#include <cstddef>

// ---------------------------------------------------------------------------
// Sizes: C=512,H=4,W=4,SPLIT=4,WC=1 -> L=2048, B=16, gates=4*L=8192
// Weights per tensor: [2][8192][2048] fp32 (33,554,432 elems)
// ---------------------------------------------------------------------------

typedef __attribute__((ext_vector_type(8))) short short8;   // 8 x bf16
typedef __attribute__((ext_vector_type(4))) short short4v;
typedef __attribute__((ext_vector_type(4))) float f32x4;

#define LD    2048
#define NBATCH 16
#define WT_ELEMS 33554432ull      // shorts (or floats) per weight tensor (2 layers)
#define LAYER_W  16777216ull      // 8192*2048

__device__ __forceinline__ short f2bf(float f) {
    union { float f; unsigned u; } c; c.f = f;
    unsigned u = c.u;
    unsigned r = (u + 0x7FFFu + ((u >> 16) & 1u)) >> 16;
    return (short)r;
}

__device__ __forceinline__ float sigmoidf_(float x) { return 1.f / (1.f + __expf(-x)); }

// ---------------------------------------------------------------------------
// Weight conversion fp32 -> bf16 (4 tensors, laid out consecutively in ws)
// ---------------------------------------------------------------------------
__global__ void k_convert(const float* __restrict__ s0, const float* __restrict__ s1,
                          const float* __restrict__ s2, const float* __restrict__ s3,
                          short* __restrict__ dst)
{
    const size_t TQ = WT_ELEMS / 4;              // float4 groups per tensor
    const size_t total = 4 * TQ;
    const size_t step = (size_t)gridDim.x * blockDim.x;
    for (size_t i = (size_t)blockIdx.x * blockDim.x + threadIdx.x; i < total; i += step) {
        size_t t = i / TQ, j = i - t * TQ;
        const float* s = (t == 0) ? s0 : (t == 1) ? s1 : (t == 2) ? s2 : s3;
        f32x4 v = ((const f32x4*)s)[j];
        short4v o;
        o[0] = f2bf(v[0]); o[1] = f2bf(v[1]); o[2] = f2bf(v[2]); o[3] = f2bf(v[3]);
        ((short4v*)dst)[t * TQ + j] = o;
    }
}

// ---------------------------------------------------------------------------
// Zero-init h (parity 0, both layers) and c (both layers), both branches
// hbuf layout: [layer][parity][branch][16][2048] bf16  (layer stride 131072)
// cst  layout: [layer][branch][16][2048] fp32          (layer stride 65536)
// ---------------------------------------------------------------------------
__global__ void k_zero(short* __restrict__ hbuf, float* __restrict__ cst)
{
    int i = blockIdx.x * blockDim.x + threadIdx.x;
    if (i < 131072) cst[i] = 0.f;
    if (i < 65536) { hbuf[i] = 0; hbuf[131072 + i] = 0; }
}

// ---------------------------------------------------------------------------
// Input prep: x1/x2 -> bf16 chunks xc[s][b][l] (l = ch*4+h, chunk s = column w)
// and verbatim copies x1 -> out[1], x2 -> out[6]
// ---------------------------------------------------------------------------
__global__ void k_prep(const float* __restrict__ x1, const float* __restrict__ x2,
                       short* __restrict__ xc1, short* __restrict__ xc2,
                       float* __restrict__ out)
{
    int i = blockIdx.x * blockDim.x + threadIdx.x;   // 32768 = 16*2048
    if (i >= 32768) return;
    int b = i >> 11, l = i & 2047;
    f32x4 v1 = ((const f32x4*)x1)[i];   // x1[b, l, 0..3] along W
    f32x4 v2 = ((const f32x4*)x2)[i];
#pragma unroll
    for (int s = 0; s < 4; ++s) {
        xc1[s * 32768 + b * 2048 + l] = f2bf(v1[s]);
        xc2[s * 32768 + b * 2048 + l] = f2bf(v2[s]);
    }
    ((f32x4*)(out + 131072))[i]     = v1;   // x1_parts[0] == x1
    ((f32x4*)(out + 6 * 131072))[i] = v2;   // x2_parts[2] == x2
}

// ---------------------------------------------------------------------------
// One LSTM cell (one layer, one time step, BOTH branches).
// Block bt in [0,128): owns 16 channels (gate rows bt*16 + {0..15} + g*2048).
// 8 waves split K: waves 0-3 -> Wih (k quarter), waves 4-7 -> Whh (k quarter).
// MFMA 16x16x32 bf16, A = weight rows, B = activations^T. LDS reduce, then
// fused gate nonlinearity + c/h update.
// ---------------------------------------------------------------------------
__global__ __launch_bounds__(512) void k_cell(
    const short* __restrict__ Wih, const short* __restrict__ Whh,   // [8192][2048] bf16
    const float* __restrict__ bih, const float* __restrict__ bhh,   // [8192]
    const short* __restrict__ xA, const short* __restrict__ xB,     // [16][2048] bf16 each
    const short* __restrict__ hin,                                  // [2][16][2048] bf16
    float* __restrict__ cst,                                        // [2][16][2048] fp32 (in-place)
    short* __restrict__ hout,                                       // [2][16][2048] bf16
    float* __restrict__ svA, float* __restrict__ svB)               // optional fp32 [16][2048]
{
    __shared__ float gpart[8][4][2][16][16];   // [wave][gate][branch][row=ch][col=n]

    const int bt   = blockIdx.x;
    const int tid  = threadIdx.x;
    const int w    = tid >> 6;
    const int lane = tid & 63;
    const int r    = lane & 15;        // A row / B col
    const int g4   = lane >> 4;        // k sub-group

    const short* Wsrc = (w < 4) ? Wih : Whh;
    const short* uA   = (w < 4) ? xA : hin;
    const short* uB   = (w < 4) ? xB : (hin + NBATCH * LD);
    const int k0      = (w & 3) * 512;

    f32x4 acc[4][2];
#pragma unroll
    for (int g = 0; g < 4; ++g) { acc[g][0] = (f32x4)0.f; acc[g][1] = (f32x4)0.f; }

    const short* wb[4];
#pragma unroll
    for (int g = 0; g < 4; ++g)
        wb[g] = Wsrc + ((size_t)(g * 2048 + bt * 16 + r)) * LD + (k0 + g4 * 8);
    const short* ua = uA + r * LD + k0 + g4 * 8;
    const short* ub = uB + r * LD + k0 + g4 * 8;

#pragma unroll 2
    for (int kk = 0; kk < 512; kk += 32) {
        short8 bA = *(const short8*)(ua + kk);
        short8 bB = *(const short8*)(ub + kk);
#pragma unroll
        for (int g = 0; g < 4; ++g) {
            short8 av = *(const short8*)(wb[g] + kk);
            acc[g][0] = __builtin_amdgcn_mfma_f32_16x16x32_bf16(av, bA, acc[g][0], 0, 0, 0);
            acc[g][1] = __builtin_amdgcn_mfma_f32_16x16x32_bf16(av, bB, acc[g][1], 0, 0, 0);
        }
    }

#pragma unroll
    for (int g = 0; g < 4; ++g)
#pragma unroll
        for (int nt = 0; nt < 2; ++nt)
#pragma unroll
            for (int q = 0; q < 4; ++q)
                gpart[w][g][nt][g4 * 4 + q][r] = acc[g][nt][q];
    __syncthreads();

    // reduce + elementwise: thread -> (branch, channel-local, batch)
    const int br  = tid >> 8;
    const int chl = (tid >> 4) & 15;
    const int n   = tid & 15;

    float gi = 0.f, gf = 0.f, gg = 0.f, go = 0.f;
#pragma unroll
    for (int ww = 0; ww < 8; ++ww) {
        gi += gpart[ww][0][br][chl][n];
        gf += gpart[ww][1][br][chl][n];
        gg += gpart[ww][2][br][chl][n];
        go += gpart[ww][3][br][chl][n];
    }
    const int ch = bt * 16 + chl;
    gi += bih[ch]            + bhh[ch];
    gf += bih[2048 + ch]     + bhh[2048 + ch];
    gg += bih[2 * 2048 + ch] + bhh[2 * 2048 + ch];
    go += bih[3 * 2048 + ch] + bhh[3 * 2048 + ch];

    const size_t idx = ((size_t)br * NBATCH + n) * LD + ch;
    float cold = cst[idx];
    float cn = sigmoidf_(gf) * cold + sigmoidf_(gi) * tanhf(gg);
    float hn = sigmoidf_(go) * tanhf(cn);
    cst[idx]  = cn;
    hout[idx] = f2bf(hn);
    if (br == 0) { if (svA) svA[(size_t)n * LD + ch] = hn; }
    else         { if (svB) svB[(size_t)n * LD + ch] = hn; }
}

// ---------------------------------------------------------------------------
// Scatter saved decoder outputs into out[2..5]
// SA slots: 0=de1, 1..7=p1..p7 ; SB slots: 0=de2, 1..7=q1..q7
// out2 = [de1,p1,p2,p3]; out3 = [p4..p7]; out4 = [q7,q6,q5,q4]; out5 = [q3,q2,q1,de2]
// ---------------------------------------------------------------------------
__global__ void k_outs(const float* __restrict__ SA, const float* __restrict__ SB,
                       float* __restrict__ out)
{
    int i = blockIdx.x * blockDim.x + threadIdx.x;   // 4*131072
    if (i >= 4 * 131072) return;
    int q  = i >> 17;
    int rr = i & 131071;
    int w  = rr & 3;
    int l  = (rr >> 2) & 2047;
    int b  = rr >> 13;
    const float* src;
    if (q == 0)      src = SA + (size_t)w       * 32768;
    else if (q == 1) src = SA + (size_t)(4 + w) * 32768;
    else if (q == 2) src = SB + (size_t)(7 - w) * 32768;
    else             src = SB + (size_t)(3 - w) * 32768;
    out[(size_t)(2 + q) * 131072 + rr] = src[(size_t)b * 2048 + l];
}

// ---------------------------------------------------------------------------
// 1x1 conv over mid = concat(x1_parts[1], x2_parts[1]) + leaky relu -> out[0]
// block = (b, h, w); 512 threads = output channels
// ---------------------------------------------------------------------------
__global__ __launch_bounds__(512) void k_conv(
    const float* __restrict__ Wc, const float* __restrict__ bc,
    const float* __restrict__ SA, const float* __restrict__ SB,
    float* __restrict__ out)
{
    __shared__ float mid[1024];
    int blk = blockIdx.x;            // 0..255
    int b = blk >> 4, hw = blk & 15, h = hw >> 2, w = hw & 3;
    int o = threadIdx.x;             // 0..511
    mid[o]       = SA[(size_t)w       * 32768 + (size_t)b * 2048 + o * 4 + h];
    mid[o + 512] = SB[(size_t)(3 - w) * 32768 + (size_t)b * 2048 + o * 4 + h];
    __syncthreads();
    float acc = bc[o];
    const f32x4* wr = (const f32x4*)(Wc + (size_t)o * 1024);
#pragma unroll 4
    for (int i2 = 0; i2 < 256; ++i2) {
        f32x4 wv = wr[i2];
        acc += wv[0] * mid[i2 * 4] + wv[1] * mid[i2 * 4 + 1]
             + wv[2] * mid[i2 * 4 + 2] + wv[3] * mid[i2 * 4 + 3];
    }
    out[(size_t)b * 8192 + o * 16 + h * 4 + w] = acc > 0.f ? acc : 0.2f * acc;
}

__global__ void k_wsfail(float* out) { if (threadIdx.x == 0 && blockIdx.x == 0) out[0] = -7.7e7f; }

// ---------------------------------------------------------------------------
extern "C" void kernel_launch(void* const* d_in, const int* in_sizes, int n_in,
                              void* d_out, int out_size, void* d_ws, size_t ws_size,
                              hipStream_t stream)
{
    const float* x1      = (const float*)d_in[0];
    const float* x2      = (const float*)d_in[1];
    const float* enc_Wih = (const float*)d_in[2];
    const float* enc_Whh = (const float*)d_in[3];
    const float* enc_bih = (const float*)d_in[4];
    const float* enc_bhh = (const float*)d_in[5];
    const float* dec_Wih = (const float*)d_in[6];
    const float* dec_Whh = (const float*)d_in[7];
    const float* dec_bih = (const float*)d_in[8];
    const float* dec_bhh = (const float*)d_in[9];
    const float* conv_W  = (const float*)d_in[10];
    const float* conv_b  = (const float*)d_in[11];
    float* out = (float*)d_out;

    // workspace layout
    short* Wb  = (short*)d_ws;                 // 4 * WT_ELEMS bf16
    short* xc1 = Wb + 4 * WT_ELEMS;            // 4*16*2048
    short* xc2 = xc1 + 131072;
    short* hbuf = xc2 + 131072;                // [2][2][2][16][2048] bf16
    float* cst  = (float*)(hbuf + 262144);     // [2][2][16][2048] fp32
    float* SA   = cst + 131072;                // 8 slots * [16][2048]
    float* SB   = SA + 262144;
    size_t need = (size_t)((char*)(SB + 262144) - (char*)d_ws);
    if (ws_size < need) { k_wsfail<<<1, 64, 0, stream>>>(out); return; }

    k_convert<<<2048, 256, 0, stream>>>(enc_Wih, enc_Whh, dec_Wih, dec_Whh, Wb);
    k_zero<<<512, 256, 0, stream>>>(hbuf, cst);
    k_prep<<<128, 256, 0, stream>>>(x1, x2, xc1, xc2, out);

    auto hB = [&](int layer, int par) { return hbuf + layer * 131072 + par * 65536; };

    for (int t = 1; t <= 15; ++t) {
        const bool enc = (t <= 4);
        const short* Wih_b = Wb + (enc ? 0 : 2 * WT_ELEMS);
        const short* Whh_b = Wb + (enc ? WT_ELEMS : 3 * WT_ELEMS);
        const float* bihs = enc ? enc_bih : dec_bih;
        const float* bhhs = enc ? enc_bhh : dec_bhh;

        // ---- layer 0 input ----
        const short *xA, *xB;
        if (t <= 4)      { xA = xc2 + (size_t)(t - 1) * 32768; xB = xc1 + (size_t)(4 - t) * 32768; }
        else if (t <= 8) { xA = xc1 + (size_t)(t - 5) * 32768; xB = xc2 + (size_t)(8 - t) * 32768; }
        else             { const short* hp = hB(1, (t - 1) & 1); xA = hp; xB = hp + 32768; }

        k_cell<<<128, 512, 0, stream>>>(Wih_b, Whh_b, bihs, bhhs,
            xA, xB, hB(0, (t - 1) & 1), cst, hB(0, t & 1), nullptr, nullptr);

        // ---- layer 1 (input = layer 0's new h) ----
        const short* hx = hB(0, t & 1);
        float* svA = nullptr; float* svB = nullptr;
        if (t >= 8) { svA = SA + (size_t)(t - 8) * 32768; svB = SB + (size_t)(t - 8) * 32768; }

        k_cell<<<128, 512, 0, stream>>>(Wih_b + LAYER_W, Whh_b + LAYER_W,
            bihs + 8192, bhhs + 8192,
            hx, hx + 32768, hB(1, (t - 1) & 1), cst + 65536, hB(1, t & 1), svA, svB);
    }

    k_outs<<<1024, 512, 0, stream>>>(SA, SB, out);
    k_conv<<<256, 512, 0, stream>>>(conv_W, conv_b, SA, SB, out);
}

// Round 2
// 950.954 us; speedup vs baseline: 1.0356x; 1.0356x over previous
//
#include <hip/hip_runtime.h>
#include <cstdint>
#include <cstddef>

// ---------------------------------------------------------------------------
// Sizes: C=512,H=4,W=4,SPLIT=4,WC=1 -> L=2048, B=16, gates=4*L=8192
// Weights per tensor: [2][8192][2048] fp32 (33,554,432 elems)
// ---------------------------------------------------------------------------

typedef __attribute__((ext_vector_type(8))) short short8;   // 8 x bf16
typedef __attribute__((ext_vector_type(4))) short short4v;
typedef __attribute__((ext_vector_type(4))) float f32x4;

#define LD    2048
#define NBATCH 16
#define WT_ELEMS 33554432ull      // shorts (or floats) per weight tensor (2 layers)
#define LAYER_W  16777216ull      // 8192*2048

__device__ __forceinline__ short f2bf(float f) {
    union { float f; unsigned u; } c; c.f = f;
    unsigned u = c.u;
    unsigned r = (u + 0x7FFFu + ((u >> 16) & 1u)) >> 16;
    return (short)r;
}

__device__ __forceinline__ float sigmoidf_(float x) { return 1.f / (1.f + __expf(-x)); }

// ---------------------------------------------------------------------------
// Weight conversion fp32 -> bf16.
// Processing order = argument order (s0 first). dst slot = (t+2)&3 so that
// callers pass DEC tensors first (slots 2,3) and ENC last (slots 0,1):
// enc bf16 ends up freshest in L3 for steps 1-4.
// Non-temporal loads: the fp32 source is never re-read -> don't thrash L3.
// ---------------------------------------------------------------------------
__global__ void k_convert(const float* __restrict__ s0, const float* __restrict__ s1,
                          const float* __restrict__ s2, const float* __restrict__ s3,
                          short* __restrict__ dst)
{
    const size_t TQ = WT_ELEMS / 4;              // float4 groups per tensor (2^23)
    const size_t total = 4 * TQ;
    const size_t step = (size_t)gridDim.x * blockDim.x;
    for (size_t i = (size_t)blockIdx.x * blockDim.x + threadIdx.x; i < total; i += step) {
        size_t t = i >> 23, j = i & (TQ - 1);
        const float* s = (t == 0) ? s0 : (t == 1) ? s1 : (t == 2) ? s2 : s3;
        size_t slot = (t + 2) & 3;
        f32x4 v = __builtin_nontemporal_load((const f32x4*)s + j);
        short4v o;
        o[0] = f2bf(v[0]); o[1] = f2bf(v[1]); o[2] = f2bf(v[2]); o[3] = f2bf(v[3]);
        ((short4v*)dst)[slot * TQ + j] = o;
    }
}

// ---------------------------------------------------------------------------
// Zero-init h (parity 0, both layers) and c (both layers), both branches
// hbuf layout: [layer][parity][branch][16][2048] bf16  (layer stride 131072)
// cst  layout: [layer][branch][16][2048] fp32          (layer stride 65536)
// ---------------------------------------------------------------------------
__global__ void k_zero(short* __restrict__ hbuf, float* __restrict__ cst)
{
    int i = blockIdx.x * blockDim.x + threadIdx.x;
    if (i < 131072) cst[i] = 0.f;
    if (i < 65536) { hbuf[i] = 0; hbuf[131072 + i] = 0; }
}

// ---------------------------------------------------------------------------
// Input prep: x1/x2 -> bf16 chunks xc[s][b][l] (l = ch*4+h, chunk s = column w)
// and verbatim copies x1 -> out[1], x2 -> out[6]
// ---------------------------------------------------------------------------
__global__ void k_prep(const float* __restrict__ x1, const float* __restrict__ x2,
                       short* __restrict__ xc1, short* __restrict__ xc2,
                       float* __restrict__ out)
{
    int i = blockIdx.x * blockDim.x + threadIdx.x;   // 32768 = 16*2048
    if (i >= 32768) return;
    int b = i >> 11, l = i & 2047;
    f32x4 v1 = ((const f32x4*)x1)[i];   // x1[b, l, 0..3] along W
    f32x4 v2 = ((const f32x4*)x2)[i];
#pragma unroll
    for (int s = 0; s < 4; ++s) {
        xc1[s * 32768 + b * 2048 + l] = f2bf(v1[s]);
        xc2[s * 32768 + b * 2048 + l] = f2bf(v2[s]);
    }
    ((f32x4*)(out + 131072))[i]     = v1;   // x1_parts[0] == x1
    ((f32x4*)(out + 6 * 131072))[i] = v2;   // x2_parts[2] == x2
}

// ---------------------------------------------------------------------------
// One LSTM cell (one layer, one time step, BOTH branches).
// Grid 512: block bt owns 4 channels (ch = bt*4 + 0..3). The 16 MFMA A-rows
// pack 4 gates x 4 channels: A row r -> weight row (r>>2)*2048 + bt*4 + (r&3).
// 8 waves split K 8 ways (4 Wih segs of 512, 4 Whh segs of 512).
// Inner loop: 1 weight load + 2 act loads + 2 MFMAs (branch A, branch B).
// LDS reduce (17 KB) + fused gate nonlinearity + c/h update.
// ---------------------------------------------------------------------------
__global__ __launch_bounds__(512, 4) void k_cell(
    const short* __restrict__ Wih, const short* __restrict__ Whh,   // [8192][2048] bf16
    const float* __restrict__ bih, const float* __restrict__ bhh,   // [8192]
    const short* __restrict__ xA, const short* __restrict__ xB,     // [16][2048] bf16 each
    const short* __restrict__ hin,                                  // [2][16][2048] bf16
    float* __restrict__ cst,                                        // [2][16][2048] fp32 (in-place)
    short* __restrict__ hout,                                       // [2][16][2048] bf16
    float* __restrict__ svA, float* __restrict__ svB)               // optional fp32 [16][2048]
{
    __shared__ float gpart[8][2][16][17];   // [wave][branch][m-row][col=n] (+1 pad)

    const int bt   = blockIdx.x;
    const int tid  = threadIdx.x;
    const int w    = tid >> 6;
    const int lane = tid & 63;
    const int r    = lane & 15;        // A row index / B col (batch)
    const int g4   = lane >> 4;        // k sub-group (8 elems each)

    const short* Wsrc = (w < 4) ? Wih : Whh;
    const short* uA   = (w < 4) ? xA : hin;
    const short* uB   = (w < 4) ? xB : (hin + NBATCH * LD);
    const int k0      = (w & 3) * 512;

    // A row r -> gate r>>2, channel-local r&3
    const int wrow = (r >> 2) * 2048 + bt * 4 + (r & 3);

    const short* wp = Wsrc + (size_t)wrow * LD + k0 + g4 * 8;
    const short* ap = uA + r * LD + k0 + g4 * 8;
    const short* bp = uB + r * LD + k0 + g4 * 8;

    f32x4 accA = {0.f, 0.f, 0.f, 0.f};
    f32x4 accB = {0.f, 0.f, 0.f, 0.f};

#pragma unroll
    for (int kk = 0; kk < 512; kk += 32) {
        short8 wv = *(const short8*)(wp + kk);
        short8 av = *(const short8*)(ap + kk);
        short8 bv = *(const short8*)(bp + kk);
        accA = __builtin_amdgcn_mfma_f32_16x16x32_bf16(wv, av, accA, 0, 0, 0);
        accB = __builtin_amdgcn_mfma_f32_16x16x32_bf16(wv, bv, accB, 0, 0, 0);
    }

    // C layout: col = lane&15 (= batch n), row m = g4*4 + q
#pragma unroll
    for (int q = 0; q < 4; ++q) {
        gpart[w][0][g4 * 4 + q][r] = accA[q];
        gpart[w][1][g4 * 4 + q][r] = accB[q];
    }
    __syncthreads();

    // reduce + elementwise: 128 threads -> (branch, channel-local, batch)
    if (tid < 128) {
        const int br  = tid >> 6;
        const int chl = (tid >> 4) & 3;
        const int n   = tid & 15;

        float gi = 0.f, gf = 0.f, gg = 0.f, go = 0.f;
#pragma unroll
        for (int ww = 0; ww < 8; ++ww) {
            gi += gpart[ww][br][chl][n];          // gate 0: m = 0*4+chl
            gf += gpart[ww][br][4 + chl][n];      // gate 1
            gg += gpart[ww][br][8 + chl][n];      // gate 2
            go += gpart[ww][br][12 + chl][n];     // gate 3
        }
        const int ch = bt * 4 + chl;
        gi += bih[ch]            + bhh[ch];
        gf += bih[2048 + ch]     + bhh[2048 + ch];
        gg += bih[2 * 2048 + ch] + bhh[2 * 2048 + ch];
        go += bih[3 * 2048 + ch] + bhh[3 * 2048 + ch];

        const size_t idx = ((size_t)br * NBATCH + n) * LD + ch;
        float cold = cst[idx];
        float cn = sigmoidf_(gf) * cold + sigmoidf_(gi) * tanhf(gg);
        float hn = sigmoidf_(go) * tanhf(cn);
        cst[idx]  = cn;
        hout[idx] = f2bf(hn);
        if (br == 0) { if (svA) svA[(size_t)n * LD + ch] = hn; }
        else         { if (svB) svB[(size_t)n * LD + ch] = hn; }
    }
}

// ---------------------------------------------------------------------------
// Scatter saved decoder outputs into out[2..5]
// SA slots: 0=de1, 1..7=p1..p7 ; SB slots: 0=de2, 1..7=q1..q7
// out2 = [de1,p1,p2,p3]; out3 = [p4..p7]; out4 = [q7,q6,q5,q4]; out5 = [q3,q2,q1,de2]
// ---------------------------------------------------------------------------
__global__ void k_outs(const float* __restrict__ SA, const float* __restrict__ SB,
                       float* __restrict__ out)
{
    int i = blockIdx.x * blockDim.x + threadIdx.x;   // 4*131072
    if (i >= 4 * 131072) return;
    int q  = i >> 17;
    int rr = i & 131071;
    int w  = rr & 3;
    int l  = (rr >> 2) & 2047;
    int b  = rr >> 13;
    const float* src;
    if (q == 0)      src = SA + (size_t)w       * 32768;
    else if (q == 1) src = SA + (size_t)(4 + w) * 32768;
    else if (q == 2) src = SB + (size_t)(7 - w) * 32768;
    else             src = SB + (size_t)(3 - w) * 32768;
    out[(size_t)(2 + q) * 131072 + rr] = src[(size_t)b * 2048 + l];
}

// ---------------------------------------------------------------------------
// 1x1 conv over mid = concat(x1_parts[1], x2_parts[1]) + leaky relu -> out[0]
// block = (b, h, w); 512 threads = output channels
// ---------------------------------------------------------------------------
__global__ __launch_bounds__(512) void k_conv(
    const float* __restrict__ Wc, const float* __restrict__ bc,
    const float* __restrict__ SA, const float* __restrict__ SB,
    float* __restrict__ out)
{
    __shared__ float mid[1024];
    int blk = blockIdx.x;            // 0..255
    int b = blk >> 4, hw = blk & 15, h = hw >> 2, w = hw & 3;
    int o = threadIdx.x;             // 0..511
    mid[o]       = SA[(size_t)w       * 32768 + (size_t)b * 2048 + o * 4 + h];
    mid[o + 512] = SB[(size_t)(3 - w) * 32768 + (size_t)b * 2048 + o * 4 + h];
    __syncthreads();
    float acc = bc[o];
    const f32x4* wr = (const f32x4*)(Wc + (size_t)o * 1024);
#pragma unroll 4
    for (int i2 = 0; i2 < 256; ++i2) {
        f32x4 wv = wr[i2];
        acc += wv[0] * mid[i2 * 4] + wv[1] * mid[i2 * 4 + 1]
             + wv[2] * mid[i2 * 4 + 2] + wv[3] * mid[i2 * 4 + 3];
    }
    out[(size_t)b * 8192 + o * 16 + h * 4 + w] = acc > 0.f ? acc : 0.2f * acc;
}

__global__ void k_wsfail(float* out) { if (threadIdx.x == 0 && blockIdx.x == 0) out[0] = -7.7e7f; }

// ---------------------------------------------------------------------------
extern "C" void kernel_launch(void* const* d_in, const int* in_sizes, int n_in,
                              void* d_out, int out_size, void* d_ws, size_t ws_size,
                              hipStream_t stream)
{
    const float* x1      = (const float*)d_in[0];
    const float* x2      = (const float*)d_in[1];
    const float* enc_Wih = (const float*)d_in[2];
    const float* enc_Whh = (const float*)d_in[3];
    const float* enc_bih = (const float*)d_in[4];
    const float* enc_bhh = (const float*)d_in[5];
    const float* dec_Wih = (const float*)d_in[6];
    const float* dec_Whh = (const float*)d_in[7];
    const float* dec_bih = (const float*)d_in[8];
    const float* dec_bhh = (const float*)d_in[9];
    const float* conv_W  = (const float*)d_in[10];
    const float* conv_b  = (const float*)d_in[11];
    float* out = (float*)d_out;

    // workspace layout
    short* Wb  = (short*)d_ws;                 // 4 * WT_ELEMS bf16 (slots: enc_Wih, enc_Whh, dec_Wih, dec_Whh)
    short* xc1 = Wb + 4 * WT_ELEMS;            // 4*16*2048
    short* xc2 = xc1 + 131072;
    short* hbuf = xc2 + 131072;                // [2][2][2][16][2048] bf16
    float* cst  = (float*)(hbuf + 262144);     // [2][2][16][2048] fp32
    float* SA   = cst + 131072;                // 8 slots * [16][2048]
    float* SB   = SA + 262144;
    size_t need = (size_t)((char*)(SB + 262144) - (char*)d_ws);
    if (ws_size < need) { k_wsfail<<<1, 64, 0, stream>>>(out); return; }

    // convert dec FIRST, enc LAST (slot = (t+2)&3) so enc weights are L3-hot
    k_convert<<<2048, 256, 0, stream>>>(dec_Wih, dec_Whh, enc_Wih, enc_Whh, Wb);
    k_zero<<<512, 256, 0, stream>>>(hbuf, cst);
    k_prep<<<128, 256, 0, stream>>>(x1, x2, xc1, xc2, out);

    auto hB = [&](int layer, int par) { return hbuf + layer * 131072 + par * 65536; };

    for (int t = 1; t <= 15; ++t) {
        const bool enc = (t <= 4);
        const short* Wih_b = Wb + (enc ? 0 : 2 * WT_ELEMS);
        const short* Whh_b = Wb + (enc ? WT_ELEMS : 3 * WT_ELEMS);
        const float* bihs = enc ? enc_bih : dec_bih;
        const float* bhhs = enc ? enc_bhh : dec_bhh;

        // ---- layer 0 input ----
        const short *xA, *xB;
        if (t <= 4)      { xA = xc2 + (size_t)(t - 1) * 32768; xB = xc1 + (size_t)(4 - t) * 32768; }
        else if (t <= 8) { xA = xc1 + (size_t)(t - 5) * 32768; xB = xc2 + (size_t)(8 - t) * 32768; }
        else             { const short* hp = hB(1, (t - 1) & 1); xA = hp; xB = hp + 32768; }

        k_cell<<<512, 512, 0, stream>>>(Wih_b, Whh_b, bihs, bhhs,
            xA, xB, hB(0, (t - 1) & 1), cst, hB(0, t & 1), nullptr, nullptr);

        // ---- layer 1 (input = layer 0's new h) ----
        const short* hx = hB(0, t & 1);
        float* svA = nullptr; float* svB = nullptr;
        if (t >= 8) { svA = SA + (size_t)(t - 8) * 32768; svB = SB + (size_t)(t - 8) * 32768; }

        k_cell<<<512, 512, 0, stream>>>(Wih_b + LAYER_W, Whh_b + LAYER_W,
            bihs + 8192, bhhs + 8192,
            hx, hx + 32768, hB(1, (t - 1) & 1), cst + 65536, hB(1, t & 1), svA, svB);
    }

    k_outs<<<1024, 512, 0, stream>>>(SA, SB, out);
    k_conv<<<256, 512, 0, stream>>>(conv_W, conv_b, SA, SB, out);
}

// Round 3
// 678.280 us; speedup vs baseline: 1.4519x; 1.4020x over previous
//
#include <hip/hip_runtime.h>
#include <cstdint>
#include <cstddef>

// ---------------------------------------------------------------------------
// Sizes: C=512,H=4,W=4,SPLIT=4,WC=1 -> L=2048, B=16, gates=4*L=8192
// Weight matrices: 8 of [8192][2048] fp32 (enc/dec x ih/hh x layer0/1)
// Packed layout: mat -> 512 ch-tiles x 64 k-steps, each a 16x32 bf16 fragment
// stored in MFMA lane order (lane l gets 8 bf16 at frag*512 + l*8).
// Fragment element map: A-row r = gate(r>>2), chl(r&3); k = ks*32 + (l>>4)*8 + j.
// Activations use the same per-fragment packing with col = batch n (l&15).
// ---------------------------------------------------------------------------

typedef __attribute__((ext_vector_type(8))) short short8;   // 8 x bf16
typedef __attribute__((ext_vector_type(4))) float f32x4;

#define LD    2048
#define NBATCH 16
#define LAYER_W  16777216ull      // elems per [8192][2048] matrix (= packed mat stride)

__device__ __forceinline__ short f2bf(float f) {
    union { float f; unsigned u; } c; c.f = f;
    unsigned u = c.u;
    unsigned r = (u + 0x7FFFu + ((u >> 16) & 1u)) >> 16;
    return (short)r;
}

__device__ __forceinline__ float sigmoidf_(float x) { return 1.f / (1.f + __expf(-x)); }

// packed offset for activation element (batch n, feature k)
__device__ __forceinline__ int apos(int n, int k) {
    return ((k >> 5) << 9) + ((((k >> 3) & 3) << 4) + n) * 8 + (k & 7);
}

// ---------------------------------------------------------------------------
// Pack one [8192][2048] fp32 matrix into fragment-ordered bf16.
// One wave per fragment (grid-stride). Writes are 1KB-contiguous per wave.
// ---------------------------------------------------------------------------
__global__ __launch_bounds__(256) void k_pack(const float* __restrict__ src,
                                              short* __restrict__ dst)
{
    int wv   = (blockIdx.x * blockDim.x + threadIdx.x) >> 6;
    int nw   = (gridDim.x * blockDim.x) >> 6;
    int lane = threadIdx.x & 63;
    int r = lane & 15, g4 = lane >> 4;
    for (int F = wv; F < 32768; F += nw) {
        int bt = F >> 6, ks = F & 63;
        int row = (r >> 2) * 2048 + bt * 4 + (r & 3);
        const float* s = src + (size_t)row * 2048 + ks * 32 + g4 * 8;
        f32x4 v0 = __builtin_nontemporal_load((const f32x4*)s);
        f32x4 v1 = __builtin_nontemporal_load((const f32x4*)s + 1);
        short8 o;
        o[0] = f2bf(v0[0]); o[1] = f2bf(v0[1]); o[2] = f2bf(v0[2]); o[3] = f2bf(v0[3]);
        o[4] = f2bf(v1[0]); o[5] = f2bf(v1[1]); o[6] = f2bf(v1[2]); o[7] = f2bf(v1[3]);
        *(short8*)(dst + ((size_t)F << 9) + lane * 8) = o;
    }
}

// ---------------------------------------------------------------------------
// Zero-init h (parity 0, both layers) and c
// hbuf: [layer][parity][branch][32768] bf16 ; cst: [layer][branch][16][2048] f32
// ---------------------------------------------------------------------------
__global__ void k_zero(short* __restrict__ hbuf, float* __restrict__ cst)
{
    int i = blockIdx.x * blockDim.x + threadIdx.x;
    if (i < 131072) cst[i] = 0.f;
    if (i < 65536) { hbuf[i] = 0; hbuf[131072 + i] = 0; }
}

// ---------------------------------------------------------------------------
// Input prep: x1/x2 -> packed bf16 chunks xc[s] (s = column w), plus verbatim
// copies x1 -> out[1], x2 -> out[6]
// ---------------------------------------------------------------------------
__global__ void k_prep(const float* __restrict__ x1, const float* __restrict__ x2,
                       short* __restrict__ xc1, short* __restrict__ xc2,
                       float* __restrict__ out)
{
    int i = blockIdx.x * blockDim.x + threadIdx.x;   // 32768 = 16*2048
    if (i >= 32768) return;
    int b = i >> 11, l = i & 2047;
    f32x4 v1 = ((const f32x4*)x1)[i];   // x1[b, l, w=0..3]
    f32x4 v2 = ((const f32x4*)x2)[i];
    int p = apos(b, l);
#pragma unroll
    for (int s = 0; s < 4; ++s) {
        xc1[s * 32768 + p] = f2bf(v1[s]);
        xc2[s * 32768 + p] = f2bf(v2[s]);
    }
    ((f32x4*)(out + 131072))[i]     = v1;   // x1_parts[0] == x1
    ((f32x4*)(out + 6 * 131072))[i] = v2;   // x2_parts[2] == x2
}

// ---------------------------------------------------------------------------
// LSTM cell, both branches. Dual-job: blocks [0,512) run jA, [512,1024) jB.
// Block owns 4 channels; 8 waves split K (4x Wih quarters, 4x Whh quarters).
// All hot-loop loads are 1KB-contiguous fragment streams.
// ---------------------------------------------------------------------------
struct CellJob {
    const short *Wih, *Whh;        // packed [512][64][512] bf16
    const float *bih, *bhh;        // [8192] fp32
    const short *xA, *xB, *hin;    // packed acts (hin: 2 branches x 32768)
    float *cst;                    // [2][16][2048] fp32 in-place
    short *hout;                   // packed [2][32768]
    float *svA, *svB;              // optional fp32 [16][2048]
};

__global__ __launch_bounds__(512, 4) void k_cell(CellJob jA, CellJob jB)
{
    __shared__ float gpart[8][2][16][17];

    const CellJob& J = (blockIdx.x < 512) ? jA : jB;
    const int bt   = blockIdx.x & 511;
    const int tid  = threadIdx.x;
    const int w    = tid >> 6;
    const int lane = tid & 63;
    const int r    = lane & 15;
    const int g4   = lane >> 4;
    const int kq   = w & 3;

    const short* Wsrc = (w < 4) ? J.Wih : J.Whh;
    const short* uA   = (w < 4) ? J.xA : J.hin;
    const short* uB   = (w < 4) ? J.xB : (J.hin + 32768);

    const short* wp = Wsrc + (((size_t)bt * 64 + kq * 16) << 9) + lane * 8;
    const short* ap = uA + ((kq * 16) << 9) + lane * 8;
    const short* bp = uB + ((kq * 16) << 9) + lane * 8;

    f32x4 accA = {0.f, 0.f, 0.f, 0.f};
    f32x4 accB = {0.f, 0.f, 0.f, 0.f};

#pragma unroll
    for (int half = 0; half < 2; ++half) {
        short8 wreg[8];
#pragma unroll
        for (int i = 0; i < 8; ++i)
            wreg[i] = *(const short8*)(wp + ((half * 8 + i) << 9));
#pragma unroll
        for (int i = 0; i < 8; ++i) {
            short8 av = *(const short8*)(ap + ((half * 8 + i) << 9));
            short8 bv = *(const short8*)(bp + ((half * 8 + i) << 9));
            accA = __builtin_amdgcn_mfma_f32_16x16x32_bf16(wreg[i], av, accA, 0, 0, 0);
            accB = __builtin_amdgcn_mfma_f32_16x16x32_bf16(wreg[i], bv, accB, 0, 0, 0);
        }
    }

    // C layout: col = lane&15, row m = g4*4+q  (m -> gate m>>2, chl m&3)
#pragma unroll
    for (int q = 0; q < 4; ++q) {
        gpart[w][0][g4 * 4 + q][r] = accA[q];
        gpart[w][1][g4 * 4 + q][r] = accB[q];
    }
    __syncthreads();

    if (tid < 128) {
        const int br  = tid >> 6;
        const int chl = (tid >> 4) & 3;
        const int n   = tid & 15;

        float gi = 0.f, gf = 0.f, gg = 0.f, go = 0.f;
#pragma unroll
        for (int ww = 0; ww < 8; ++ww) {
            gi += gpart[ww][br][chl][n];
            gf += gpart[ww][br][4 + chl][n];
            gg += gpart[ww][br][8 + chl][n];
            go += gpart[ww][br][12 + chl][n];
        }
        const int ch = bt * 4 + chl;
        gi += J.bih[ch]            + J.bhh[ch];
        gf += J.bih[2048 + ch]     + J.bhh[2048 + ch];
        gg += J.bih[2 * 2048 + ch] + J.bhh[2 * 2048 + ch];
        go += J.bih[3 * 2048 + ch] + J.bhh[3 * 2048 + ch];

        const size_t idx = ((size_t)br * NBATCH + n) * LD + ch;
        float cold = J.cst[idx];
        float cn = sigmoidf_(gf) * cold + sigmoidf_(gi) * tanhf(gg);
        float hn = sigmoidf_(go) * tanhf(cn);
        J.cst[idx] = cn;
        J.hout[br * 32768 + apos(n, ch)] = f2bf(hn);
        if (br == 0) { if (J.svA) J.svA[(size_t)n * LD + ch] = hn; }
        else         { if (J.svB) J.svB[(size_t)n * LD + ch] = hn; }
    }
}

// ---------------------------------------------------------------------------
// Scatter saved decoder outputs into out[2..5]
// ---------------------------------------------------------------------------
__global__ void k_outs(const float* __restrict__ SA, const float* __restrict__ SB,
                       float* __restrict__ out)
{
    int i = blockIdx.x * blockDim.x + threadIdx.x;   // 4*131072
    if (i >= 4 * 131072) return;
    int q  = i >> 17;
    int rr = i & 131071;
    int w  = rr & 3;
    int l  = (rr >> 2) & 2047;
    int b  = rr >> 13;
    const float* src;
    if (q == 0)      src = SA + (size_t)w       * 32768;
    else if (q == 1) src = SA + (size_t)(4 + w) * 32768;
    else if (q == 2) src = SB + (size_t)(7 - w) * 32768;
    else             src = SB + (size_t)(3 - w) * 32768;
    out[(size_t)(2 + q) * 131072 + rr] = src[(size_t)b * 2048 + l];
}

// ---------------------------------------------------------------------------
// 1x1 conv + leaky relu -> out[0]
// ---------------------------------------------------------------------------
__global__ __launch_bounds__(512) void k_conv(
    const float* __restrict__ Wc, const float* __restrict__ bc,
    const float* __restrict__ SA, const float* __restrict__ SB,
    float* __restrict__ out)
{
    __shared__ float mid[1024];
    int blk = blockIdx.x;            // 0..255
    int b = blk >> 4, hw = blk & 15, h = hw >> 2, w = hw & 3;
    int o = threadIdx.x;             // 0..511
    mid[o]       = SA[(size_t)w       * 32768 + (size_t)b * 2048 + o * 4 + h];
    mid[o + 512] = SB[(size_t)(3 - w) * 32768 + (size_t)b * 2048 + o * 4 + h];
    __syncthreads();
    float acc = bc[o];
    const f32x4* wr = (const f32x4*)(Wc + (size_t)o * 1024);
#pragma unroll 4
    for (int i2 = 0; i2 < 256; ++i2) {
        f32x4 wv = wr[i2];
        acc += wv[0] * mid[i2 * 4] + wv[1] * mid[i2 * 4 + 1]
             + wv[2] * mid[i2 * 4 + 2] + wv[3] * mid[i2 * 4 + 3];
    }
    out[(size_t)b * 8192 + o * 16 + h * 4 + w] = acc > 0.f ? acc : 0.2f * acc;
}

__global__ void k_wsfail(float* out) { if (threadIdx.x == 0 && blockIdx.x == 0) out[0] = -7.7e7f; }

// ---------------------------------------------------------------------------
extern "C" void kernel_launch(void* const* d_in, const int* in_sizes, int n_in,
                              void* d_out, int out_size, void* d_ws, size_t ws_size,
                              hipStream_t stream)
{
    const float* x1      = (const float*)d_in[0];
    const float* x2      = (const float*)d_in[1];
    const float* enc_Wih = (const float*)d_in[2];
    const float* enc_Whh = (const float*)d_in[3];
    const float* enc_bih = (const float*)d_in[4];
    const float* enc_bhh = (const float*)d_in[5];
    const float* dec_Wih = (const float*)d_in[6];
    const float* dec_Whh = (const float*)d_in[7];
    const float* dec_bih = (const float*)d_in[8];
    const float* dec_bhh = (const float*)d_in[9];
    const float* conv_W  = (const float*)d_in[10];
    const float* conv_b  = (const float*)d_in[11];
    float* out = (float*)d_out;

    // workspace: 8 packed matrices (mat = (enc?0:4) + hh*2 + layer)
    short* Wb  = (short*)d_ws;                 // 8 * LAYER_W bf16
    short* xc1 = Wb + 8 * LAYER_W;             // 4 chunks * 32768
    short* xc2 = xc1 + 131072;
    short* hbuf = xc2 + 131072;                // [2][2][2][32768] bf16
    float* cst  = (float*)(hbuf + 262144);     // [2][2][16][2048] fp32
    float* SA   = cst + 131072;                // 8 slots * [16][2048] fp32
    float* SB   = SA + 262144;
    size_t need = (size_t)((char*)(SB + 262144) - (char*)d_ws);
    if (ws_size < need) { k_wsfail<<<1, 64, 0, stream>>>(out); return; }

    k_zero<<<512, 256, 0, stream>>>(hbuf, cst);
    k_prep<<<128, 256, 0, stream>>>(x1, x2, xc1, xc2, out);

    // pack dec first, enc last (enc L3-hot for steps 1-4)
    const float* srcs[4] = { enc_Wih, enc_Whh, dec_Wih, dec_Whh };
    for (int m = 0; m < 8; ++m) {
        int mat = (m < 4) ? (4 + m) : (m - 4);
        const float* src = srcs[mat >> 1] + (size_t)(mat & 1) * LAYER_W;
        k_pack<<<2048, 256, 0, stream>>>(src, Wb + (size_t)mat * LAYER_W);
    }

    auto hB = [&](int layer, int par) { return hbuf + layer * 131072 + par * 65536; };

    auto mkJob = [&](int t, int layer) -> CellJob {
        const bool enc = (t <= 4);
        CellJob j;
        int base = enc ? 0 : 4;
        j.Wih = Wb + (size_t)(base + layer) * LAYER_W;
        j.Whh = Wb + (size_t)(base + 2 + layer) * LAYER_W;
        j.bih = (enc ? enc_bih : dec_bih) + layer * 8192;
        j.bhh = (enc ? enc_bhh : dec_bhh) + layer * 8192;
        if (layer == 0) {
            if (t <= 4)      { j.xA = xc2 + (size_t)(t - 1) * 32768; j.xB = xc1 + (size_t)(4 - t) * 32768; }
            else if (t <= 8) { j.xA = xc1 + (size_t)(t - 5) * 32768; j.xB = xc2 + (size_t)(8 - t) * 32768; }
            else             { const short* hp = hB(1, (t - 1) & 1); j.xA = hp; j.xB = hp + 32768; }
            j.hin = hB(0, (t - 1) & 1);
            j.cst = cst;
            j.hout = hB(0, t & 1);
            j.svA = nullptr; j.svB = nullptr;
        } else {
            const short* hx = hB(0, t & 1);
            j.xA = hx; j.xB = hx + 32768;
            j.hin = hB(1, (t - 1) & 1);
            j.cst = cst + 65536;
            j.hout = hB(1, t & 1);
            j.svA = (t >= 8) ? SA + (size_t)(t - 8) * 32768 : nullptr;
            j.svB = (t >= 8) ? SB + (size_t)(t - 8) * 32768 : nullptr;
        }
        return j;
    };

    // t=1 layer0 alone
    k_cell<<<512, 512, 0, stream>>>(mkJob(1, 0), mkJob(1, 0));
    // t=2..8: layer0(t) || layer1(t-1)  (independent)
    for (int t = 2; t <= 8; ++t)
        k_cell<<<1024, 512, 0, stream>>>(mkJob(t, 0), mkJob(t - 1, 1));
    // layer1(8) alone
    k_cell<<<512, 512, 0, stream>>>(mkJob(8, 1), mkJob(8, 1));
    // AR steps: strictly serial
    for (int t = 9; t <= 15; ++t) {
        k_cell<<<512, 512, 0, stream>>>(mkJob(t, 0), mkJob(t, 0));
        k_cell<<<512, 512, 0, stream>>>(mkJob(t, 1), mkJob(t, 1));
    }

    k_outs<<<1024, 512, 0, stream>>>(SA, SB, out);
    k_conv<<<256, 512, 0, stream>>>(conv_W, conv_b, SA, SB, out);
}